// Round 4
// baseline (945.702 us; speedup 1.0000x reference)
//
#include <hip/hip_runtime.h>
#include <hip/hip_bf16.h>

// ---------------------------------------------------------------------------
// GCN 2-layer forward on MI355X (gfx950).
// REAL pipeline = round-1 config (410.8us, best): 6 launches.
//   K0 cvt_zero : weight f32->bf16 transpose + zero bcnt & bcnt_p
//   K1 fused1   : blocks [0,NBB) bucket-bin edges; blocks [NBB,..) gemm1
//   K2 scatter2 : inline 196-scan of bcnt; deg->dinv; rowptr; einfo
//   K3 agg1     : gather+fma(dinv[s]) -> relu -> a1 (bf16)
//   K4 gemm2    : g2 = dinv*(a1@W2), bf16
//   K5 agg2     : gather-add of g2 -> relu -> out (fp32)
// INSTRUMENTATION (this round only): four probe dispatches appended AFTER
// the output is complete, each an x8 internal repeat of one invisible stage
// so it lands in rocprof's top-5 with full counters:
//   P1 bin_probe : binning x8 (scratch bcnt_p; records into dead hb region,
//                  index bounded by (pos & 8191) -- no OOB possible)
//   P2 g1_probe  : gemm1 x8   (rewrites hb with identical h1 values)
//   P3 sc_probe  : scatter2 x8 (in-place identical rewrite)
//   P4 g2_probe  : gemm2 x8   (rewrites hb with identical g2 values)
// R3 crash root-cause: bcnt_p was uninitialized -> garbage rstart -> negative
// pos passed the signed guard -> OOB store. Fixed: bcnt_p zeroed in K0 and
// probe store index masked to a bounded window (store always issued, so the
// measured cost stays constant across graph replays).
// Idempotency: every real consumer in the NEXT replay reads data freshly
// rewritten by its REAL producer. Probes never write `out`.
// ---------------------------------------------------------------------------

#define DIN 256
#define DH 128
#define BKT_SHIFT 9
#define BKT_SZ 512
#define NBKT_MAX 256
#define CAP 10240
#define PROBE_REP 8

typedef __attribute__((ext_vector_type(8))) short short8;
typedef __attribute__((ext_vector_type(4))) float f32x4;
typedef __attribute__((ext_vector_type(2))) unsigned int uint2e;

__device__ __forceinline__ unsigned short f2bf(float f) {
    union { float f; unsigned int i; } c;
    c.f = f;
    unsigned int r = c.i + 0x7FFFu + ((c.i >> 16) & 1u);  // RNE
    return (unsigned short)(r >> 16);
}
__device__ __forceinline__ float bf_lo(unsigned int u) {
    union { unsigned int i; float f; } c;
    c.i = u << 16;
    return c.f;
}
__device__ __forceinline__ float bf_hi(unsigned int u) {
    union { unsigned int i; float f; } c;
    c.i = u & 0xFFFF0000u;
    return c.f;
}

// ---------------- K0: weight conversion + zero bcnt/bcnt_p ------------------
__global__ __launch_bounds__(256) void cvt_zero_k(const float* __restrict__ W1,
                                                  const float* __restrict__ W2,
                                                  unsigned short* __restrict__ Wt1,
                                                  unsigned short* __restrict__ Wt2,
                                                  int* __restrict__ bcnt,
                                                  int* __restrict__ bcnt_p, int WTB) {
    int bx = blockIdx.x;
    int t = threadIdx.x;
    if (bx >= WTB) {
        bcnt[t] = 0;
        bcnt_p[t] = 0;
        return;
    }
    int i = bx * 256 + t;
    if (i < 256 * 128) {
        int k = i >> 7, nn = i & 127;
        Wt1[(size_t)nn * 256 + k] = f2bf(W1[i]);
    } else {
        int j = i - 256 * 128;
        int k = j >> 7, nn = j & 127;
        Wt2[(size_t)nn * 128 + k] = f2bf(W2[j]);
    }
}

// ---------------- GEMM body (MFMA bf16) -------------------------------------
// G[M,128] = (SCALE ? dinv[row] : 1) * (A[M,K] @ Wt^T), bf16 out.
// Wt is [128][K] bf16. Bt LDS layout is fragment-major (stride-1 b128 reads).
template <bool A_BF16, bool SCALE>
__device__ __forceinline__ void gemm_body(unsigned short* Bt, int gb,
                                          const void* __restrict__ Av,
                                          const unsigned short* __restrict__ Wt,
                                          const float* __restrict__ dinv,
                                          unsigned short* __restrict__ Hb,
                                          int M, int K) {
    const int t = threadIdx.x;
    const int w = t >> 6;
    const int lane = t & 63;
    const int l15 = lane & 15;
    const int quad = lane >> 4;
    const int row0 = gb * 128 + w * 32;

    const float* Af = (const float*)Av;
    const unsigned short* Ab = (const unsigned short*)Av;

    f32x4 acc[2][8];
#pragma unroll
    for (int rt = 0; rt < 2; ++rt)
#pragma unroll
        for (int ct = 0; ct < 8; ++ct)
#pragma unroll
            for (int j = 0; j < 4; ++j) acc[rt][ct][j] = 0.0f;

    for (int kc = 0; kc < K; kc += 128) {
        if (kc) __syncthreads();
#pragma unroll
        for (int i = 0; i < 8; ++i) {
            int fg = w * 8 + i;
            int ks = fg >> 3, ct = fg & 7;
            int nn = ct * 16 + l15;
            int gk = ks * 32 + quad * 8;
            *(short8*)&Bt[fg * 512 + lane * 8] =
                *(const short8*)(Wt + (size_t)nn * K + kc + gk);
        }
        __syncthreads();
#pragma unroll
        for (int ks = 0; ks < 4; ++ks) {
            int kk = ks * 32 + quad * 8;
            short8 af[2];
#pragma unroll
            for (int rt = 0; rt < 2; ++rt) {
                int row = row0 + rt * 16 + l15;
                if (row < M) {
                    if (A_BF16) {
                        af[rt] = *(const short8*)(Ab + (size_t)row * K + kc + kk);
                    } else {
                        const float* p = Af + (size_t)row * K + kc + kk;
                        float4 x0 = *(const float4*)p;
                        float4 x1 = *(const float4*)(p + 4);
                        af[rt][0] = (short)f2bf(x0.x);
                        af[rt][1] = (short)f2bf(x0.y);
                        af[rt][2] = (short)f2bf(x0.z);
                        af[rt][3] = (short)f2bf(x0.w);
                        af[rt][4] = (short)f2bf(x1.x);
                        af[rt][5] = (short)f2bf(x1.y);
                        af[rt][6] = (short)f2bf(x1.z);
                        af[rt][7] = (short)f2bf(x1.w);
                    }
                } else {
#pragma unroll
                    for (int j = 0; j < 8; ++j) af[rt][j] = 0;
                }
            }
#pragma unroll
            for (int ct = 0; ct < 8; ++ct) {
                short8 bfr = *(const short8*)&Bt[(ks * 8 + ct) * 512 + lane * 8];
                acc[0][ct] = __builtin_amdgcn_mfma_f32_16x16x32_bf16(af[0], bfr, acc[0][ct], 0, 0, 0);
                acc[1][ct] = __builtin_amdgcn_mfma_f32_16x16x32_bf16(af[1], bfr, acc[1][ct], 0, 0, 0);
            }
        }
    }
#pragma unroll
    for (int rt = 0; rt < 2; ++rt)
#pragma unroll
        for (int r = 0; r < 4; ++r) {
            int row = row0 + rt * 16 + quad * 4 + r;
            if (row < M) {
                float dv = SCALE ? dinv[row] : 1.0f;
                unsigned short* o = Hb + (size_t)row * 128 + l15;
#pragma unroll
                for (int ct = 0; ct < 8; ++ct)
                    o[ct * 16] = f2bf(SCALE ? dv * acc[rt][ct][r] : acc[rt][ct][r]);
            }
        }
}

// ---------------- K1: fused bucket-binning + gemm1 --------------------------
// record: src | (dlow9 << 20)  (src < 2^17)
struct SmemFused {
    union {
        unsigned short Bt[16384];
        struct {
            int hist[NBKT_MAX];
            int rstart[NBKT_MAX];
        } bk;
    };
};

__global__ __launch_bounds__(256) void fused1_k(const int* __restrict__ src,
                                                const int* __restrict__ dst,
                                                int* __restrict__ bcnt,
                                                int* __restrict__ tmp, int e, int n,
                                                int NBB,
                                                const float* __restrict__ x,
                                                const unsigned short* __restrict__ Wt1,
                                                unsigned short* __restrict__ hb, int M) {
    __shared__ SmemFused sm;
    int bx = blockIdx.x;
    int t = threadIdx.x;
    if (bx < NBB) {
        int* hist = sm.bk.hist;
        int* rstart = sm.bk.rstart;
        int chunk = (e + NBB - 1) / NBB;
        int beg = bx * chunk, end = min(e, beg + chunk);

        hist[t] = 0;
        __syncthreads();
        for (int i = beg + t; i < end; i += 256) atomicAdd(&hist[dst[i] >> BKT_SHIFT], 1);
        __syncthreads();
        int nbkt = (n + BKT_SZ - 1) >> BKT_SHIFT;
        int h = hist[t];
        if (t < nbkt && h > 0) rstart[t] = atomicAdd(&bcnt[t], h);
        __syncthreads();
        hist[t] = 0;
        __syncthreads();
        for (int i = beg + t; i < end; i += 256) {
            int d = dst[i];
            int b = d >> BKT_SHIFT;
            int o = atomicAdd(&hist[b], 1);
            tmp[(size_t)b * CAP + rstart[b] + o] = src[i] | ((d & (BKT_SZ - 1)) << 20);
        }
        return;
    }
    // gemm1: unscaled h1 = bf16(x @ W1^T)
    gemm_body<false, false>(sm.Bt, bx - NBB, x, Wt1, nullptr, hb, M, DIN);
}

// ---------------- K2: per-bucket scan + deg->dinv + scatter -----------------
__global__ __launch_bounds__(1024) void scatter2_k(const int* __restrict__ tmp,
                                                   const int* __restrict__ bcnt,
                                                   float* __restrict__ dinv,
                                                   int* __restrict__ rowptr,
                                                   int* __restrict__ einfo, int n,
                                                   int nbkt) {
    __shared__ int hist[BKT_SZ];
    __shared__ int scn[BKT_SZ];
    __shared__ int cur[BKT_SZ];
    int b = blockIdx.x;
    int t = threadIdx.x;
    int lo = b << BKT_SHIFT;
    int nn = min(n - lo, BKT_SZ);
    int cnt = bcnt[b];
    const int* rec = tmp + (size_t)b * CAP;

    // inline exclusive scan of bcnt[0..nbkt) -> bas (replaces scan196 kernel)
    if (t < 256) scn[t] = (t < nbkt) ? bcnt[t] : 0;
    __syncthreads();
    for (int off = 1; off < 256; off <<= 1) {
        int v = 0;
        if (t < 256 && t >= off) v = scn[t - off];
        __syncthreads();
        if (t < 256) scn[t] += v;
        __syncthreads();
    }
    int bas = scn[b] - cnt;  // exclusive prefix of this bucket
    if (b == nbkt - 1 && t == 0) rowptr[n] = scn[nbkt - 1];  // == E
    __syncthreads();

    if (t < BKT_SZ) hist[t] = 0;
    __syncthreads();
    for (int i = t; i < cnt; i += 1024) atomicAdd(&hist[(rec[i] >> 20) & (BKT_SZ - 1)], 1);
    __syncthreads();
    if (t < BKT_SZ) scn[t] = hist[t];
    __syncthreads();
    for (int off = 1; off < BKT_SZ; off <<= 1) {
        int v = 0;
        if (t < BKT_SZ && t >= off) v = scn[t - off];
        __syncthreads();
        if (t < BKT_SZ) scn[t] += v;
        __syncthreads();
    }
    if (t < nn) {
        int excl = bas + scn[t] - hist[t];
        dinv[lo + t] = 1.0f / sqrtf((float)(hist[t] + 1));
        rowptr[lo + t] = excl;
        cur[t] = excl;
    }
    __syncthreads();
    for (int i = t; i < cnt; i += 1024) {
        int r = rec[i];
        int dlow = (r >> 20) & (BKT_SZ - 1);
        int pos = atomicAdd(&cur[dlow], 1);
        einfo[pos] = r & 0xFFFFF;
    }
}

// ---------------- aggregation ----------------
template <bool SCALE_SRC, bool OUT_BF16>
__global__ __launch_bounds__(256) void agg_k(const unsigned short* __restrict__ Hb,
                                             const int* __restrict__ rowptr,
                                             const int* __restrict__ einfo,
                                             const float* __restrict__ dinv,
                                             const float* __restrict__ bias,
                                             void* __restrict__ out, int n) {
    int v = blockIdx.x * 4 + (threadIdx.x >> 6);
    int lane = threadIdx.x & 63;
    if (v >= n) return;
    int l = lane & 31, half = lane >> 5;
    const uint2* __restrict__ H = (const uint2*)Hb;  // row = 32 x uint2
    float dv = dinv[v];
    float a0 = 0.f, a1 = 0.f, a2 = 0.f, a3 = 0.f;
    if (half == 0) {
        uint2 hv = H[(size_t)v * 32 + l];  // self-loop term
        if (SCALE_SRC) {
            a0 = dv * bf_lo(hv.x); a1 = dv * bf_hi(hv.x);
            a2 = dv * bf_lo(hv.y); a3 = dv * bf_hi(hv.y);
        } else {
            a0 = bf_lo(hv.x); a1 = bf_hi(hv.x);
            a2 = bf_lo(hv.y); a3 = bf_hi(hv.y);
        }
    }
    int end = rowptr[v + 1];
    int i = rowptr[v] + half;
    for (; i + 6 < end; i += 8) {
        int s0 = __builtin_nontemporal_load(&einfo[i]);
        int s1 = __builtin_nontemporal_load(&einfo[i + 2]);
        int s2 = __builtin_nontemporal_load(&einfo[i + 4]);
        int s3 = __builtin_nontemporal_load(&einfo[i + 6]);
        float d0 = 1.f, d1 = 1.f, d2 = 1.f, d3 = 1.f;
        if (SCALE_SRC) { d0 = dinv[s0]; d1 = dinv[s1]; d2 = dinv[s2]; d3 = dinv[s3]; }
        uint2 v0 = H[(size_t)s0 * 32 + l];
        uint2 v1 = H[(size_t)s1 * 32 + l];
        uint2 v2 = H[(size_t)s2 * 32 + l];
        uint2 v3 = H[(size_t)s3 * 32 + l];
        if (SCALE_SRC) {
            a0 = fmaf(d0, bf_lo(v0.x), a0); a1 = fmaf(d0, bf_hi(v0.x), a1);
            a2 = fmaf(d0, bf_lo(v0.y), a2); a3 = fmaf(d0, bf_hi(v0.y), a3);
            a0 = fmaf(d1, bf_lo(v1.x), a0); a1 = fmaf(d1, bf_hi(v1.x), a1);
            a2 = fmaf(d1, bf_lo(v1.y), a2); a3 = fmaf(d1, bf_hi(v1.y), a3);
            a0 = fmaf(d2, bf_lo(v2.x), a0); a1 = fmaf(d2, bf_hi(v2.x), a1);
            a2 = fmaf(d2, bf_lo(v2.y), a2); a3 = fmaf(d2, bf_hi(v2.y), a3);
            a0 = fmaf(d3, bf_lo(v3.x), a0); a1 = fmaf(d3, bf_hi(v3.x), a1);
            a2 = fmaf(d3, bf_lo(v3.y), a2); a3 = fmaf(d3, bf_hi(v3.y), a3);
        } else {
            a0 += bf_lo(v0.x); a1 += bf_hi(v0.x); a2 += bf_lo(v0.y); a3 += bf_hi(v0.y);
            a0 += bf_lo(v1.x); a1 += bf_hi(v1.x); a2 += bf_lo(v1.y); a3 += bf_hi(v1.y);
            a0 += bf_lo(v2.x); a1 += bf_hi(v2.x); a2 += bf_lo(v2.y); a3 += bf_hi(v2.y);
            a0 += bf_lo(v3.x); a1 += bf_hi(v3.x); a2 += bf_lo(v3.y); a3 += bf_hi(v3.y);
        }
    }
    for (; i < end; i += 2) {
        int s = __builtin_nontemporal_load(&einfo[i]);
        float ds = SCALE_SRC ? dinv[s] : 1.f;
        uint2 vv = H[(size_t)s * 32 + l];
        if (SCALE_SRC) {
            a0 = fmaf(ds, bf_lo(vv.x), a0); a1 = fmaf(ds, bf_hi(vv.x), a1);
            a2 = fmaf(ds, bf_lo(vv.y), a2); a3 = fmaf(ds, bf_hi(vv.y), a3);
        } else {
            a0 += bf_lo(vv.x); a1 += bf_hi(vv.x); a2 += bf_lo(vv.y); a3 += bf_hi(vv.y);
        }
    }
    a0 += __shfl_xor(a0, 32);
    a1 += __shfl_xor(a1, 32);
    a2 += __shfl_xor(a2, 32);
    a3 += __shfl_xor(a3, 32);
    if (half == 0) {
        float4 bb = ((const float4*)bias)[l];
        float o0 = fmaxf(fmaf(dv, a0, bb.x), 0.f);
        float o1 = fmaxf(fmaf(dv, a1, bb.y), 0.f);
        float o2 = fmaxf(fmaf(dv, a2, bb.z), 0.f);
        float o3 = fmaxf(fmaf(dv, a3, bb.w), 0.f);
        if (OUT_BF16) {
            uint2e p;
            p.x = (unsigned int)f2bf(o0) | ((unsigned int)f2bf(o1) << 16);
            p.y = (unsigned int)f2bf(o2) | ((unsigned int)f2bf(o3) << 16);
            __builtin_nontemporal_store(p, (uint2e*)out + (size_t)v * 32 + l);
        } else {
            f32x4 o = {o0, o1, o2, o3};
            __builtin_nontemporal_store(o, (f32x4*)out + (size_t)v * 32 + l);
        }
    }
}

// ---------------- K4: layer-2 GEMM ------------------------------------------
__global__ __launch_bounds__(256) void gemm2_k(const unsigned short* __restrict__ A,
                                               const unsigned short* __restrict__ Wt,
                                               const float* __restrict__ dinv,
                                               unsigned short* __restrict__ Hb,
                                               int M, int K) {
    __shared__ unsigned short Bt[16384];
    gemm_body<true, true>(Bt, blockIdx.x, A, Wt, dinv, Hb, M, K);
}

// ======================= PROBES (instrumentation only) ======================
// P1: binning x8. bcnt_p zeroed in K0; record writes masked into [0,8192)
// of each bucket window (always-issued store, bounded address).
__global__ __launch_bounds__(256) void bin_probe_k(const int* __restrict__ src,
                                                   const int* __restrict__ dst,
                                                   int* __restrict__ bcnt_p,
                                                   int* __restrict__ tmp_p, int e,
                                                   int n, int NBB) {
    __shared__ int hist[NBKT_MAX];
    __shared__ int rstart[NBKT_MAX];
    int bx = blockIdx.x;
    int t = threadIdx.x;
    int nbkt = (n + BKT_SZ - 1) >> BKT_SHIFT;
    int chunk = (e + NBB - 1) / NBB;
    int beg = bx * chunk, end = min(e, beg + chunk);
    for (int r = 0; r < PROBE_REP; ++r) {
        __syncthreads();
        hist[t] = 0;
        __syncthreads();
        for (int i = beg + t; i < end; i += 256) atomicAdd(&hist[dst[i] >> BKT_SHIFT], 1);
        __syncthreads();
        int h = hist[t];
        if (t < nbkt && h > 0) rstart[t] = atomicAdd(&bcnt_p[t], h);
        __syncthreads();
        hist[t] = 0;
        __syncthreads();
        for (int i = beg + t; i < end; i += 256) {
            int d = dst[i];
            int b = d >> BKT_SHIFT;
            int o = atomicAdd(&hist[b], 1);
            int pos = (rstart[b] + o) & 8191;  // bounded, always in-window
            tmp_p[(size_t)b * CAP + pos] = src[i] | ((d & (BKT_SZ - 1)) << 20);
        }
    }
}

// P2: gemm1 x8 (identical in-place rewrite of hb).
__global__ __launch_bounds__(256) void g1_probe_k(const float* __restrict__ x,
                                                  const unsigned short* __restrict__ Wt1,
                                                  unsigned short* __restrict__ hb, int M) {
    __shared__ unsigned short Bt[16384];
    for (int r = 0; r < PROBE_REP; ++r) {
        if (r) __syncthreads();
        gemm_body<false, false>(Bt, blockIdx.x, x, Wt1, nullptr, hb, M, DIN);
    }
}

// P3: scatter2 x8 (identical in-place rewrite of dinv/rowptr/einfo).
__global__ __launch_bounds__(1024) void sc_probe_k(const int* __restrict__ tmp,
                                                   const int* __restrict__ bcnt,
                                                   float* __restrict__ dinv,
                                                   int* __restrict__ rowptr,
                                                   int* __restrict__ einfo, int n,
                                                   int nbkt) {
    __shared__ int hist[BKT_SZ];
    __shared__ int scn[BKT_SZ];
    __shared__ int cur[BKT_SZ];
    int b = blockIdx.x;
    int t = threadIdx.x;
    int lo = b << BKT_SHIFT;
    int nn = min(n - lo, BKT_SZ);
    int cnt = bcnt[b];
    const int* rec = tmp + (size_t)b * CAP;
    for (int r = 0; r < PROBE_REP; ++r) {
        __syncthreads();
        if (t < 256) scn[t] = (t < nbkt) ? bcnt[t] : 0;
        __syncthreads();
        for (int off = 1; off < 256; off <<= 1) {
            int v = 0;
            if (t < 256 && t >= off) v = scn[t - off];
            __syncthreads();
            if (t < 256) scn[t] += v;
            __syncthreads();
        }
        int bas = scn[b] - cnt;
        if (b == nbkt - 1 && t == 0) rowptr[n] = scn[nbkt - 1];
        __syncthreads();
        if (t < BKT_SZ) hist[t] = 0;
        __syncthreads();
        for (int i = t; i < cnt; i += 1024) atomicAdd(&hist[(rec[i] >> 20) & (BKT_SZ - 1)], 1);
        __syncthreads();
        if (t < BKT_SZ) scn[t] = hist[t];
        __syncthreads();
        for (int off = 1; off < BKT_SZ; off <<= 1) {
            int v = 0;
            if (t < BKT_SZ && t >= off) v = scn[t - off];
            __syncthreads();
            if (t < BKT_SZ) scn[t] += v;
            __syncthreads();
        }
        if (t < nn) {
            int excl = bas + scn[t] - hist[t];
            dinv[lo + t] = 1.0f / sqrtf((float)(hist[t] + 1));
            rowptr[lo + t] = excl;
            cur[t] = excl;
        }
        __syncthreads();
        for (int i = t; i < cnt; i += 1024) {
            int rr = rec[i];
            int dlow = (rr >> 20) & (BKT_SZ - 1);
            int pos = atomicAdd(&cur[dlow], 1);
            einfo[pos] = rr & 0xFFFFF;
        }
    }
}

// P4: gemm2 x8 (identical in-place rewrite of hb with g2 values).
__global__ __launch_bounds__(256) void g2_probe_k(const unsigned short* __restrict__ A,
                                                  const unsigned short* __restrict__ Wt,
                                                  const float* __restrict__ dinv,
                                                  unsigned short* __restrict__ Hb,
                                                  int M, int K) {
    __shared__ unsigned short Bt[16384];
    for (int r = 0; r < PROBE_REP; ++r) {
        if (r) __syncthreads();
        gemm_body<true, true>(Bt, blockIdx.x, A, Wt, dinv, Hb, M, K);
    }
}

static inline size_t align_up(size_t x, size_t a) { return (x + a - 1) & ~(a - 1); }

extern "C" void kernel_launch(void* const* d_in, const int* in_sizes, int n_in,
                              void* d_out, int out_size, void* d_ws, size_t ws_size,
                              hipStream_t stream) {
    const float* x  = (const float*)d_in[0];
    const int*   ei = (const int*)d_in[1];
    const float* W1 = (const float*)d_in[2];
    const float* b1 = (const float*)d_in[3];
    const float* W2 = (const float*)d_in[4];
    const float* b2 = (const float*)d_in[5];

    const int N = in_sizes[0] / DIN;   // 100000
    const int E = in_sizes[1] / 2;     // 1600000
    const int* src = ei;
    const int* dst = ei + E;
    const int NBKT = (N + BKT_SZ - 1) >> BKT_SHIFT;  // 196

    // workspace partition (round-1 layout + tiny bcnt_p)
    char* base_p = (char*)d_ws;
    size_t off = 0;
    int* bcnt = (int*)(base_p + off);       off = align_up(off + 256 * 4, 256);
    int* rowptr = (int*)(base_p + off);     off = align_up(off + (size_t)(N + 1) * 4, 256);
    float* dinv = (float*)(base_p + off);   off = align_up(off + (size_t)N * 4, 256);
    int* tmp = (int*)(base_p + off);        off = align_up(off + (size_t)NBKT * CAP * 4, 256);
    int* einfo = (int*)(base_p + off);      off = align_up(off + (size_t)E * 4, 256);
    unsigned short* Wt1 = (unsigned short*)(base_p + off); off = align_up(off + (size_t)128 * 256 * 2, 256);
    unsigned short* Wt2 = (unsigned short*)(base_p + off); off = align_up(off + (size_t)128 * 128 * 2, 256);
    unsigned short* hb  = (unsigned short*)(base_p + off); off = align_up(off + (size_t)N * 128 * 2, 256);
    unsigned short* a1b = (unsigned short*)(base_p + off); off = align_up(off + (size_t)N * 128 * 2, 256);
    int* bcnt_p = (int*)(base_p + off);     off = align_up(off + 256 * 4, 256);
    // P1's record scratch aliases the hb region (dead between agg1 and g1_probe;
    // fully rewritten by g1_probe, then g2_probe, then next iter's real fused1).
    int* tmp_p = (int*)hb;  // needs 8.03MB <= 25.6MB

    float* out = (float*)d_out;

    const int NBB = 512;                                  // bucket blocks
    const int WTB = (256 * 128 + 128 * 128 + 255) / 256;  // 192 weight blocks
    const int GB = (N + 127) / 128;                       // 782 gemm blocks

    // ---------------- real pipeline (identical to round-1 410.8us) ---------
    cvt_zero_k<<<WTB + 1, 256, 0, stream>>>(W1, W2, Wt1, Wt2, bcnt, bcnt_p, WTB);
    fused1_k<<<NBB + GB, 256, 0, stream>>>(src, dst, bcnt, tmp, E, N, NBB, x, Wt1, hb, N);
    scatter2_k<<<NBKT, 1024, 0, stream>>>(tmp, bcnt, dinv, rowptr, einfo, N, NBKT);
    agg_k<true, true><<<(N + 3) / 4, 256, 0, stream>>>(hb, rowptr, einfo, dinv, b1, a1b, N);
    gemm2_k<<<GB, 256, 0, stream>>>(a1b, Wt2, dinv, hb, N, DH);
    agg_k<false, false><<<(N + 3) / 4, 256, 0, stream>>>(hb, rowptr, einfo, dinv, b2, out, N);

    // ---------------- probes (output already written; all idempotent) ------
    bin_probe_k<<<NBB, 256, 0, stream>>>(src, dst, bcnt_p, tmp_p, E, N, NBB);
    g1_probe_k<<<GB, 256, 0, stream>>>(x, Wt1, hb, N);
    sc_probe_k<<<NBKT, 1024, 0, stream>>>(tmp, bcnt, dinv, rowptr, einfo, N, NBKT);
    g2_probe_k<<<GB, 256, 0, stream>>>(a1b, Wt2, dinv, hb, N, DH);
}

// Round 5
// 557.537 us; speedup vs baseline: 1.6962x; 1.6962x over previous
//
#include <hip/hip_runtime.h>
#include <hip/hip_bf16.h>

// ---------------------------------------------------------------------------
// GCN 2-layer forward on MI355X (gfx950).
// R4 probe findings: launch gaps ~= 0 (534.9us probe delta == 8x sum of probe
// kernels exactly); warm stage kernels are small; the ~213us middle therefore
// lives in the bucket CSR build (tmp scatter write + cross-XCD re-read +
// 196-block scatter2). This round replaces it with a direct atomic CSR build
// that never materializes records:
//   M0 memset     : deg[N] ++ bsum[256] = 0  (one contiguous region)
//   K0 cvt_k      : W1,W2 f32 -> Wt1,Wt2 bf16 transposed     (192 blocks)
//   K1 fused_a    : blocks [0,DEGB): per-edge atomicAdd(deg[dst]) + LDS
//                   bucket-hist -> one atomicAdd(bsum[b]) per block;
//                   blocks [DEGB,..): gemm1  h1 = bf16(x @ W1^T)  (unscaled;
//                   dinv not ready yet -> agg1 applies dinv[s] via fma)
//   K2 scan_k     : 196-scan(bsum) + 512-scan(deg) -> rowptr, cur, dinv
//   K3 scatter_k  : einfo[atomicAdd(cur[dst])] = src   (4B/edge, only write)
//   K4 agg1       : gather+fma(dinv[s]) -> relu -> a1 (bf16)
//   K5 gemm2      : g2 = dinv*(a1@W2), bf16
//   K6 agg2       : gather-add of g2 -> relu -> out (fp32)
// Row-order in einfo becomes atomic-race-ordered (it already was); agg
// accumulates fp32 so reorder error ~2^-20 -- absmax unchanged.
// agg: 1 wave/node, half-wave per 256B row, 4 gathers in flight (R6: deeper
// no gain; MLP x latency floor ~83-87us each, accepted).
// ---------------------------------------------------------------------------

#define DIN 256
#define DH 128
#define BKT_SHIFT 9
#define BKT_SZ 512
#define NBKT_MAX 256

typedef __attribute__((ext_vector_type(8))) short short8;
typedef __attribute__((ext_vector_type(4))) float f32x4;
typedef __attribute__((ext_vector_type(2))) unsigned int uint2e;

__device__ __forceinline__ unsigned short f2bf(float f) {
    union { float f; unsigned int i; } c;
    c.f = f;
    unsigned int r = c.i + 0x7FFFu + ((c.i >> 16) & 1u);  // RNE
    return (unsigned short)(r >> 16);
}
__device__ __forceinline__ float bf_lo(unsigned int u) {
    union { unsigned int i; float f; } c;
    c.i = u << 16;
    return c.f;
}
__device__ __forceinline__ float bf_hi(unsigned int u) {
    union { unsigned int i; float f; } c;
    c.i = u & 0xFFFF0000u;
    return c.f;
}

// ---------------- K0: weight conversion ------------------------------------
__global__ __launch_bounds__(256) void cvt_k(const float* __restrict__ W1,
                                             const float* __restrict__ W2,
                                             unsigned short* __restrict__ Wt1,
                                             unsigned short* __restrict__ Wt2) {
    int i = blockIdx.x * 256 + threadIdx.x;
    if (i < 256 * 128) {
        int k = i >> 7, nn = i & 127;
        Wt1[(size_t)nn * 256 + k] = f2bf(W1[i]);
    } else if (i < 256 * 128 + 128 * 128) {
        int j = i - 256 * 128;
        int k = j >> 7, nn = j & 127;
        Wt2[(size_t)nn * 128 + k] = f2bf(W2[j]);
    }
}

// ---------------- GEMM body (MFMA bf16) -------------------------------------
// G[M,128] = (SCALE ? dinv[row] : 1) * (A[M,K] @ Wt^T), bf16 out.
// Wt is [128][K] bf16. Bt LDS layout is fragment-major (stride-1 b128 reads).
template <bool A_BF16, bool SCALE>
__device__ __forceinline__ void gemm_body(unsigned short* Bt, int gb,
                                          const void* __restrict__ Av,
                                          const unsigned short* __restrict__ Wt,
                                          const float* __restrict__ dinv,
                                          unsigned short* __restrict__ Hb,
                                          int M, int K) {
    const int t = threadIdx.x;
    const int w = t >> 6;
    const int lane = t & 63;
    const int l15 = lane & 15;
    const int quad = lane >> 4;
    const int row0 = gb * 128 + w * 32;

    const float* Af = (const float*)Av;
    const unsigned short* Ab = (const unsigned short*)Av;

    f32x4 acc[2][8];
#pragma unroll
    for (int rt = 0; rt < 2; ++rt)
#pragma unroll
        for (int ct = 0; ct < 8; ++ct)
#pragma unroll
            for (int j = 0; j < 4; ++j) acc[rt][ct][j] = 0.0f;

    for (int kc = 0; kc < K; kc += 128) {
        if (kc) __syncthreads();
#pragma unroll
        for (int i = 0; i < 8; ++i) {
            int fg = w * 8 + i;
            int ks = fg >> 3, ct = fg & 7;
            int nn = ct * 16 + l15;
            int gk = ks * 32 + quad * 8;
            *(short8*)&Bt[fg * 512 + lane * 8] =
                *(const short8*)(Wt + (size_t)nn * K + kc + gk);
        }
        __syncthreads();
#pragma unroll
        for (int ks = 0; ks < 4; ++ks) {
            int kk = ks * 32 + quad * 8;
            short8 af[2];
#pragma unroll
            for (int rt = 0; rt < 2; ++rt) {
                int row = row0 + rt * 16 + l15;
                if (row < M) {
                    if (A_BF16) {
                        af[rt] = *(const short8*)(Ab + (size_t)row * K + kc + kk);
                    } else {
                        const float* p = Af + (size_t)row * K + kc + kk;
                        float4 x0 = *(const float4*)p;
                        float4 x1 = *(const float4*)(p + 4);
                        af[rt][0] = (short)f2bf(x0.x);
                        af[rt][1] = (short)f2bf(x0.y);
                        af[rt][2] = (short)f2bf(x0.z);
                        af[rt][3] = (short)f2bf(x0.w);
                        af[rt][4] = (short)f2bf(x1.x);
                        af[rt][5] = (short)f2bf(x1.y);
                        af[rt][6] = (short)f2bf(x1.z);
                        af[rt][7] = (short)f2bf(x1.w);
                    }
                } else {
#pragma unroll
                    for (int j = 0; j < 8; ++j) af[rt][j] = 0;
                }
            }
#pragma unroll
            for (int ct = 0; ct < 8; ++ct) {
                short8 bfr = *(const short8*)&Bt[(ks * 8 + ct) * 512 + lane * 8];
                acc[0][ct] = __builtin_amdgcn_mfma_f32_16x16x32_bf16(af[0], bfr, acc[0][ct], 0, 0, 0);
                acc[1][ct] = __builtin_amdgcn_mfma_f32_16x16x32_bf16(af[1], bfr, acc[1][ct], 0, 0, 0);
            }
        }
    }
#pragma unroll
    for (int rt = 0; rt < 2; ++rt)
#pragma unroll
        for (int r = 0; r < 4; ++r) {
            int row = row0 + rt * 16 + quad * 4 + r;
            if (row < M) {
                float dv = SCALE ? dinv[row] : 1.0f;
                unsigned short* o = Hb + (size_t)row * 128 + l15;
#pragma unroll
                for (int ct = 0; ct < 8; ++ct)
                    o[ct * 16] = f2bf(SCALE ? dv * acc[rt][ct][r] : acc[rt][ct][r]);
            }
        }
}

// ---------------- K1: fused degree-count + gemm1 ----------------------------
struct SmemFused {
    union {
        unsigned short Bt[16384];
        int hist[NBKT_MAX];
    };
};

__global__ __launch_bounds__(256) void fused_a(const int* __restrict__ dst,
                                               int* __restrict__ deg,
                                               int* __restrict__ bsum,
                                               int e, int n, int DEGB,
                                               const float* __restrict__ x,
                                               const unsigned short* __restrict__ Wt1,
                                               unsigned short* __restrict__ hb, int M) {
    __shared__ SmemFused sm;
    int bx = blockIdx.x;
    int t = threadIdx.x;
    if (bx < DEGB) {
        int nbkt = (n + BKT_SZ - 1) >> BKT_SHIFT;
        int chunk = (e + DEGB - 1) / DEGB;
        int beg = bx * chunk, end = min(e, beg + chunk);
        sm.hist[t] = 0;
        __syncthreads();
        for (int i = beg + t; i < end; i += 256) {
            int d = dst[i];
            atomicAdd(&deg[d], 1);
            atomicAdd(&sm.hist[d >> BKT_SHIFT], 1);
        }
        __syncthreads();
        int h = sm.hist[t];
        if (t < nbkt && h > 0) atomicAdd(&bsum[t], h);
        return;
    }
    // gemm1: unscaled h1 = bf16(x @ W1^T)
    gemm_body<false, false>(sm.Bt, bx - DEGB, x, Wt1, nullptr, hb, M, DIN);
}

// ---------------- K2: scan (bsum 196-scan + deg 512-scan) -------------------
// rowptr[v] = exclusive prefix of deg; cur[v] = rowptr[v]; dinv = rsqrt(deg+1)
__global__ __launch_bounds__(512) void scan_k(const int* __restrict__ deg,
                                              const int* __restrict__ bsum,
                                              int* __restrict__ rowptr,
                                              int* __restrict__ cur,
                                              float* __restrict__ dinv,
                                              int n, int nbkt) {
    __shared__ int s196[256];
    __shared__ int sc[512];
    int b = blockIdx.x;
    int t = threadIdx.x;
    int lo = b << BKT_SHIFT;
    int nn = min(n - lo, BKT_SZ);

    if (t < 256) s196[t] = (t < nbkt) ? bsum[t] : 0;
    __syncthreads();
    for (int off = 1; off < 256; off <<= 1) {
        int v = 0;
        if (t < 256 && t >= off) v = s196[t - off];
        __syncthreads();
        if (t < 256) s196[t] += v;
        __syncthreads();
    }
    int bas = (b == 0) ? 0 : s196[b - 1];  // exclusive prefix of this bucket
    if (b == nbkt - 1 && t == 0) rowptr[n] = s196[nbkt - 1];  // == E

    int dv_ = (t < nn) ? deg[lo + t] : 0;
    sc[t] = dv_;
    __syncthreads();
    for (int off = 1; off < 512; off <<= 1) {
        int v = 0;
        if (t >= off) v = sc[t - off];
        __syncthreads();
        sc[t] += v;
        __syncthreads();
    }
    if (t < nn) {
        int excl = bas + sc[t] - dv_;
        rowptr[lo + t] = excl;
        cur[lo + t] = excl;
        dinv[lo + t] = 1.0f / sqrtf((float)(dv_ + 1));
    }
}

// ---------------- K3: direct atomic scatter ---------------------------------
__global__ __launch_bounds__(256) void scatter_k(const int* __restrict__ src,
                                                 const int* __restrict__ dst,
                                                 int* __restrict__ cur,
                                                 int* __restrict__ einfo, int e) {
    int i = blockIdx.x * 256 + threadIdx.x;
    if (i < e) {
        int d = dst[i];
        int pos = atomicAdd(&cur[d], 1);
        einfo[pos] = src[i];
    }
}

// ---------------- aggregation ----------------
// SCALE_SRC: out[v] = relu(dinv[v]*(sum dinv[s]*h[s] + dinv[v]*h[v]) + b)
// else:      out[v] = relu(dinv[v]*(sum g[s] + g[v]) + b)   (g pre-scaled)
// 1 wave/node; half-wave per 256B bf16 row (uint2/lane); halves take even/odd
// edges; 4 gathers in flight.
template <bool SCALE_SRC, bool OUT_BF16>
__global__ __launch_bounds__(256) void agg_k(const unsigned short* __restrict__ Hb,
                                             const int* __restrict__ rowptr,
                                             const int* __restrict__ einfo,
                                             const float* __restrict__ dinv,
                                             const float* __restrict__ bias,
                                             void* __restrict__ out, int n) {
    int v = blockIdx.x * 4 + (threadIdx.x >> 6);
    int lane = threadIdx.x & 63;
    if (v >= n) return;
    int l = lane & 31, half = lane >> 5;
    const uint2* __restrict__ H = (const uint2*)Hb;  // row = 32 x uint2
    float dv = dinv[v];
    float a0 = 0.f, a1 = 0.f, a2 = 0.f, a3 = 0.f;
    if (half == 0) {
        uint2 hv = H[(size_t)v * 32 + l];  // self-loop term
        if (SCALE_SRC) {
            a0 = dv * bf_lo(hv.x); a1 = dv * bf_hi(hv.x);
            a2 = dv * bf_lo(hv.y); a3 = dv * bf_hi(hv.y);
        } else {
            a0 = bf_lo(hv.x); a1 = bf_hi(hv.x);
            a2 = bf_lo(hv.y); a3 = bf_hi(hv.y);
        }
    }
    int end = rowptr[v + 1];
    int i = rowptr[v] + half;
    for (; i + 6 < end; i += 8) {
        int s0 = __builtin_nontemporal_load(&einfo[i]);
        int s1 = __builtin_nontemporal_load(&einfo[i + 2]);
        int s2 = __builtin_nontemporal_load(&einfo[i + 4]);
        int s3 = __builtin_nontemporal_load(&einfo[i + 6]);
        float d0 = 1.f, d1 = 1.f, d2 = 1.f, d3 = 1.f;
        if (SCALE_SRC) { d0 = dinv[s0]; d1 = dinv[s1]; d2 = dinv[s2]; d3 = dinv[s3]; }
        uint2 v0 = H[(size_t)s0 * 32 + l];
        uint2 v1 = H[(size_t)s1 * 32 + l];
        uint2 v2 = H[(size_t)s2 * 32 + l];
        uint2 v3 = H[(size_t)s3 * 32 + l];
        if (SCALE_SRC) {
            a0 = fmaf(d0, bf_lo(v0.x), a0); a1 = fmaf(d0, bf_hi(v0.x), a1);
            a2 = fmaf(d0, bf_lo(v0.y), a2); a3 = fmaf(d0, bf_hi(v0.y), a3);
            a0 = fmaf(d1, bf_lo(v1.x), a0); a1 = fmaf(d1, bf_hi(v1.x), a1);
            a2 = fmaf(d1, bf_lo(v1.y), a2); a3 = fmaf(d1, bf_hi(v1.y), a3);
            a0 = fmaf(d2, bf_lo(v2.x), a0); a1 = fmaf(d2, bf_hi(v2.x), a1);
            a2 = fmaf(d2, bf_lo(v2.y), a2); a3 = fmaf(d2, bf_hi(v2.y), a3);
            a0 = fmaf(d3, bf_lo(v3.x), a0); a1 = fmaf(d3, bf_hi(v3.x), a1);
            a2 = fmaf(d3, bf_lo(v3.y), a2); a3 = fmaf(d3, bf_hi(v3.y), a3);
        } else {
            a0 += bf_lo(v0.x); a1 += bf_hi(v0.x); a2 += bf_lo(v0.y); a3 += bf_hi(v0.y);
            a0 += bf_lo(v1.x); a1 += bf_hi(v1.x); a2 += bf_lo(v1.y); a3 += bf_hi(v1.y);
            a0 += bf_lo(v2.x); a1 += bf_hi(v2.x); a2 += bf_lo(v2.y); a3 += bf_hi(v2.y);
            a0 += bf_lo(v3.x); a1 += bf_hi(v3.x); a2 += bf_lo(v3.y); a3 += bf_hi(v3.y);
        }
    }
    for (; i < end; i += 2) {
        int s = __builtin_nontemporal_load(&einfo[i]);
        float ds = SCALE_SRC ? dinv[s] : 1.f;
        uint2 vv = H[(size_t)s * 32 + l];
        if (SCALE_SRC) {
            a0 = fmaf(ds, bf_lo(vv.x), a0); a1 = fmaf(ds, bf_hi(vv.x), a1);
            a2 = fmaf(ds, bf_lo(vv.y), a2); a3 = fmaf(ds, bf_hi(vv.y), a3);
        } else {
            a0 += bf_lo(vv.x); a1 += bf_hi(vv.x); a2 += bf_lo(vv.y); a3 += bf_hi(vv.y);
        }
    }
    a0 += __shfl_xor(a0, 32);
    a1 += __shfl_xor(a1, 32);
    a2 += __shfl_xor(a2, 32);
    a3 += __shfl_xor(a3, 32);
    if (half == 0) {
        float4 bb = ((const float4*)bias)[l];
        float o0 = fmaxf(fmaf(dv, a0, bb.x), 0.f);
        float o1 = fmaxf(fmaf(dv, a1, bb.y), 0.f);
        float o2 = fmaxf(fmaf(dv, a2, bb.z), 0.f);
        float o3 = fmaxf(fmaf(dv, a3, bb.w), 0.f);
        if (OUT_BF16) {
            uint2e p;
            p.x = (unsigned int)f2bf(o0) | ((unsigned int)f2bf(o1) << 16);
            p.y = (unsigned int)f2bf(o2) | ((unsigned int)f2bf(o3) << 16);
            __builtin_nontemporal_store(p, (uint2e*)out + (size_t)v * 32 + l);
        } else {
            f32x4 o = {o0, o1, o2, o3};
            __builtin_nontemporal_store(o, (f32x4*)out + (size_t)v * 32 + l);
        }
    }
}

// ---------------- K5: layer-2 GEMM ------------------------------------------
__global__ __launch_bounds__(256) void gemm2_k(const unsigned short* __restrict__ A,
                                               const unsigned short* __restrict__ Wt,
                                               const float* __restrict__ dinv,
                                               unsigned short* __restrict__ Hb,
                                               int M, int K) {
    __shared__ unsigned short Bt[16384];
    gemm_body<true, true>(Bt, blockIdx.x, A, Wt, dinv, Hb, M, K);
}

static inline size_t align_up(size_t x, size_t a) { return (x + a - 1) & ~(a - 1); }

extern "C" void kernel_launch(void* const* d_in, const int* in_sizes, int n_in,
                              void* d_out, int out_size, void* d_ws, size_t ws_size,
                              hipStream_t stream) {
    const float* x  = (const float*)d_in[0];
    const int*   ei = (const int*)d_in[1];
    const float* W1 = (const float*)d_in[2];
    const float* b1 = (const float*)d_in[3];
    const float* W2 = (const float*)d_in[4];
    const float* b2 = (const float*)d_in[5];

    const int N = in_sizes[0] / DIN;   // 100000
    const int E = in_sizes[1] / 2;     // 1600000
    const int* src = ei;
    const int* dst = ei + E;
    const int NBKT = (N + BKT_SZ - 1) >> BKT_SHIFT;  // 196

    // workspace partition
    char* base_p = (char*)d_ws;
    size_t off = 0;
    int* deg = (int*)(base_p + off);        off = align_up(off + (size_t)(N + 256) * 4, 256);
    int* bsum = deg + N;                    // contiguous with deg: one memset
    int* rowptr = (int*)(base_p + off);     off = align_up(off + (size_t)(N + 1) * 4, 256);
    int* cur = (int*)(base_p + off);        off = align_up(off + (size_t)N * 4, 256);
    float* dinv = (float*)(base_p + off);   off = align_up(off + (size_t)N * 4, 256);
    int* einfo = (int*)(base_p + off);      off = align_up(off + (size_t)E * 4, 256);
    unsigned short* Wt1 = (unsigned short*)(base_p + off); off = align_up(off + (size_t)128 * 256 * 2, 256);
    unsigned short* Wt2 = (unsigned short*)(base_p + off); off = align_up(off + (size_t)128 * 128 * 2, 256);
    unsigned short* hb  = (unsigned short*)(base_p + off); off = align_up(off + (size_t)N * 128 * 2, 256);
    unsigned short* a1b = (unsigned short*)(base_p + off); off = align_up(off + (size_t)N * 128 * 2, 256);

    float* out = (float*)d_out;

    const int DEGB = 512;                                 // degree blocks
    const int WTB = (256 * 128 + 128 * 128 + 255) / 256;  // 192 weight blocks
    const int GB = (N + 127) / 128;                       // 782 gemm blocks

    // M0: zero deg[N] + bsum[256] in one shot
    hipMemsetAsync(deg, 0, (size_t)(N + 256) * sizeof(int), stream);
    // K0: weight conversion
    cvt_k<<<WTB, 256, 0, stream>>>(W1, W2, Wt1, Wt2);
    // K1: degree count (+ bucket sums) || gemm1
    fused_a<<<DEGB + GB, 256, 0, stream>>>(dst, deg, bsum, E, N, DEGB, x, Wt1, hb, N);
    // K2: scans -> rowptr, cur, dinv
    scan_k<<<NBKT, 512, 0, stream>>>(deg, bsum, rowptr, cur, dinv, N, NBKT);
    // K3: direct atomic scatter -> einfo
    scatter_k<<<(E + 255) / 256, 256, 0, stream>>>(src, dst, cur, einfo, E);
    // K4: agg1 (applies dinv[s] per source via fma)
    agg_k<true, true><<<(N + 3) / 4, 256, 0, stream>>>(hb, rowptr, einfo, dinv, b1, a1b, N);
    // K5: layer-2 GEMM
    gemm2_k<<<GB, 256, 0, stream>>>(a1b, Wt2, dinv, hb, N, DH);
    // K6: agg2 -> fp32 out
    agg_k<false, false><<<(N + 3) / 4, 256, 0, stream>>>(hb, rowptr, einfo, dinv, b2, out, N);
}

// Round 6
// 408.733 us; speedup vs baseline: 2.3137x; 1.3641x over previous
//
#include <hip/hip_runtime.h>
#include <hip/hip_bf16.h>

// ---------------------------------------------------------------------------
// GCN 2-layer forward on MI355X (gfx950).
// Pipeline = round-1 config (410.8us best) with ONE change: agg_k issues
// 8 outstanding gathers per half-wave (was 4).
// Accounting across R1/R4/R5: timed region carries ~170us of harness-reset
// overhead; optimizable time ~240us = aggs 172 + middle ~70. Aggs run at
// 2.7 TB/s, exactly Little's-law-bound: ~12KB in flight/CU vs 22KB needed
// for 6.3 TB/s. 8-deep gathers double in-flight bytes -> predict ~4+ TB/s.
//   K0 cvt_zero : weight f32->bf16 transpose + zero bcnt   (193 blocks)
//   K1 fused1   : blocks [0,NBB) bucket-bin edges; blocks [NBB,..) gemm1
//   K2 scatter2 : inline 196-scan of bcnt; deg->dinv; rowptr; einfo
//                 (bucket windows keep einfo writes CU-local -- R5 lesson:
//                 global atomic scatter = 16x write-amp, 133us)
//   K3 agg1     : gather+fma(dinv[s]) -> relu -> a1 (bf16)
//   K4 gemm2    : g2 = dinv*(a1@W2), bf16
//   K5 agg2     : gather-add of g2 -> relu -> out (fp32)
// ---------------------------------------------------------------------------

#define DIN 256
#define DH 128
#define BKT_SHIFT 9
#define BKT_SZ 512
#define NBKT_MAX 256
#define CAP 10240

typedef __attribute__((ext_vector_type(8))) short short8;
typedef __attribute__((ext_vector_type(4))) float f32x4;
typedef __attribute__((ext_vector_type(2))) unsigned int uint2e;

__device__ __forceinline__ unsigned short f2bf(float f) {
    union { float f; unsigned int i; } c;
    c.f = f;
    unsigned int r = c.i + 0x7FFFu + ((c.i >> 16) & 1u);  // RNE
    return (unsigned short)(r >> 16);
}
__device__ __forceinline__ float bf_lo(unsigned int u) {
    union { unsigned int i; float f; } c;
    c.i = u << 16;
    return c.f;
}
__device__ __forceinline__ float bf_hi(unsigned int u) {
    union { unsigned int i; float f; } c;
    c.i = u & 0xFFFF0000u;
    return c.f;
}

// ---------------- K0: weight conversion + zero bcnt -------------------------
__global__ __launch_bounds__(256) void cvt_zero_k(const float* __restrict__ W1,
                                                  const float* __restrict__ W2,
                                                  unsigned short* __restrict__ Wt1,
                                                  unsigned short* __restrict__ Wt2,
                                                  int* __restrict__ bcnt, int WTB) {
    int bx = blockIdx.x;
    int t = threadIdx.x;
    if (bx >= WTB) {
        bcnt[t] = 0;
        return;
    }
    int i = bx * 256 + t;
    if (i < 256 * 128) {
        int k = i >> 7, nn = i & 127;
        Wt1[(size_t)nn * 256 + k] = f2bf(W1[i]);
    } else {
        int j = i - 256 * 128;
        int k = j >> 7, nn = j & 127;
        Wt2[(size_t)nn * 128 + k] = f2bf(W2[j]);
    }
}

// ---------------- GEMM body (MFMA bf16) -------------------------------------
// G[M,128] = (SCALE ? dinv[row] : 1) * (A[M,K] @ Wt^T), bf16 out.
// Wt is [128][K] bf16. Bt LDS layout is fragment-major (stride-1 b128 reads).
template <bool A_BF16, bool SCALE>
__device__ __forceinline__ void gemm_body(unsigned short* Bt, int gb,
                                          const void* __restrict__ Av,
                                          const unsigned short* __restrict__ Wt,
                                          const float* __restrict__ dinv,
                                          unsigned short* __restrict__ Hb,
                                          int M, int K) {
    const int t = threadIdx.x;
    const int w = t >> 6;
    const int lane = t & 63;
    const int l15 = lane & 15;
    const int quad = lane >> 4;
    const int row0 = gb * 128 + w * 32;

    const float* Af = (const float*)Av;
    const unsigned short* Ab = (const unsigned short*)Av;

    f32x4 acc[2][8];
#pragma unroll
    for (int rt = 0; rt < 2; ++rt)
#pragma unroll
        for (int ct = 0; ct < 8; ++ct)
#pragma unroll
            for (int j = 0; j < 4; ++j) acc[rt][ct][j] = 0.0f;

    for (int kc = 0; kc < K; kc += 128) {
        if (kc) __syncthreads();
#pragma unroll
        for (int i = 0; i < 8; ++i) {
            int fg = w * 8 + i;
            int ks = fg >> 3, ct = fg & 7;
            int nn = ct * 16 + l15;
            int gk = ks * 32 + quad * 8;
            *(short8*)&Bt[fg * 512 + lane * 8] =
                *(const short8*)(Wt + (size_t)nn * K + kc + gk);
        }
        __syncthreads();
#pragma unroll
        for (int ks = 0; ks < 4; ++ks) {
            int kk = ks * 32 + quad * 8;
            short8 af[2];
#pragma unroll
            for (int rt = 0; rt < 2; ++rt) {
                int row = row0 + rt * 16 + l15;
                if (row < M) {
                    if (A_BF16) {
                        af[rt] = *(const short8*)(Ab + (size_t)row * K + kc + kk);
                    } else {
                        const float* p = Af + (size_t)row * K + kc + kk;
                        float4 x0 = *(const float4*)p;
                        float4 x1 = *(const float4*)(p + 4);
                        af[rt][0] = (short)f2bf(x0.x);
                        af[rt][1] = (short)f2bf(x0.y);
                        af[rt][2] = (short)f2bf(x0.z);
                        af[rt][3] = (short)f2bf(x0.w);
                        af[rt][4] = (short)f2bf(x1.x);
                        af[rt][5] = (short)f2bf(x1.y);
                        af[rt][6] = (short)f2bf(x1.z);
                        af[rt][7] = (short)f2bf(x1.w);
                    }
                } else {
#pragma unroll
                    for (int j = 0; j < 8; ++j) af[rt][j] = 0;
                }
            }
#pragma unroll
            for (int ct = 0; ct < 8; ++ct) {
                short8 bfr = *(const short8*)&Bt[(ks * 8 + ct) * 512 + lane * 8];
                acc[0][ct] = __builtin_amdgcn_mfma_f32_16x16x32_bf16(af[0], bfr, acc[0][ct], 0, 0, 0);
                acc[1][ct] = __builtin_amdgcn_mfma_f32_16x16x32_bf16(af[1], bfr, acc[1][ct], 0, 0, 0);
            }
        }
    }
#pragma unroll
    for (int rt = 0; rt < 2; ++rt)
#pragma unroll
        for (int r = 0; r < 4; ++r) {
            int row = row0 + rt * 16 + quad * 4 + r;
            if (row < M) {
                float dv = SCALE ? dinv[row] : 1.0f;
                unsigned short* o = Hb + (size_t)row * 128 + l15;
#pragma unroll
                for (int ct = 0; ct < 8; ++ct)
                    o[ct * 16] = f2bf(SCALE ? dv * acc[rt][ct][r] : acc[rt][ct][r]);
            }
        }
}

// ---------------- K1: fused bucket-binning + gemm1 --------------------------
// record: src | (dlow9 << 20)  (src < 2^17)
struct SmemFused {
    union {
        unsigned short Bt[16384];
        struct {
            int hist[NBKT_MAX];
            int rstart[NBKT_MAX];
        } bk;
    };
};

__global__ __launch_bounds__(256) void fused1_k(const int* __restrict__ src,
                                                const int* __restrict__ dst,
                                                int* __restrict__ bcnt,
                                                int* __restrict__ tmp, int e, int n,
                                                int NBB,
                                                const float* __restrict__ x,
                                                const unsigned short* __restrict__ Wt1,
                                                unsigned short* __restrict__ hb, int M) {
    __shared__ SmemFused sm;
    int bx = blockIdx.x;
    int t = threadIdx.x;
    if (bx < NBB) {
        int* hist = sm.bk.hist;
        int* rstart = sm.bk.rstart;
        int chunk = (e + NBB - 1) / NBB;
        int beg = bx * chunk, end = min(e, beg + chunk);

        hist[t] = 0;
        __syncthreads();
        for (int i = beg + t; i < end; i += 256) atomicAdd(&hist[dst[i] >> BKT_SHIFT], 1);
        __syncthreads();
        int nbkt = (n + BKT_SZ - 1) >> BKT_SHIFT;
        int h = hist[t];
        if (t < nbkt && h > 0) rstart[t] = atomicAdd(&bcnt[t], h);
        __syncthreads();
        hist[t] = 0;
        __syncthreads();
        for (int i = beg + t; i < end; i += 256) {
            int d = dst[i];
            int b = d >> BKT_SHIFT;
            int o = atomicAdd(&hist[b], 1);
            tmp[(size_t)b * CAP + rstart[b] + o] = src[i] | ((d & (BKT_SZ - 1)) << 20);
        }
        return;
    }
    // gemm1: unscaled h1 = bf16(x @ W1^T)
    gemm_body<false, false>(sm.Bt, bx - NBB, x, Wt1, nullptr, hb, M, DIN);
}

// ---------------- K2: per-bucket scan + deg->dinv + scatter -----------------
__global__ __launch_bounds__(1024) void scatter2_k(const int* __restrict__ tmp,
                                                   const int* __restrict__ bcnt,
                                                   float* __restrict__ dinv,
                                                   int* __restrict__ rowptr,
                                                   int* __restrict__ einfo, int n,
                                                   int nbkt) {
    __shared__ int hist[BKT_SZ];
    __shared__ int scn[BKT_SZ];
    __shared__ int cur[BKT_SZ];
    int b = blockIdx.x;
    int t = threadIdx.x;
    int lo = b << BKT_SHIFT;
    int nn = min(n - lo, BKT_SZ);
    int cnt = bcnt[b];
    const int* rec = tmp + (size_t)b * CAP;

    // inline exclusive scan of bcnt[0..nbkt) -> bas (replaces scan196 kernel)
    if (t < 256) scn[t] = (t < nbkt) ? bcnt[t] : 0;
    __syncthreads();
    for (int off = 1; off < 256; off <<= 1) {
        int v = 0;
        if (t < 256 && t >= off) v = scn[t - off];
        __syncthreads();
        if (t < 256) scn[t] += v;
        __syncthreads();
    }
    int bas = scn[b] - cnt;  // exclusive prefix of this bucket
    if (b == nbkt - 1 && t == 0) rowptr[n] = scn[nbkt - 1];  // == E
    __syncthreads();

    if (t < BKT_SZ) hist[t] = 0;
    __syncthreads();
    for (int i = t; i < cnt; i += 1024) atomicAdd(&hist[(rec[i] >> 20) & (BKT_SZ - 1)], 1);
    __syncthreads();
    if (t < BKT_SZ) scn[t] = hist[t];
    __syncthreads();
    for (int off = 1; off < BKT_SZ; off <<= 1) {
        int v = 0;
        if (t < BKT_SZ && t >= off) v = scn[t - off];
        __syncthreads();
        if (t < BKT_SZ) scn[t] += v;
        __syncthreads();
    }
    if (t < nn) {
        int excl = bas + scn[t] - hist[t];
        dinv[lo + t] = 1.0f / sqrtf((float)(hist[t] + 1));
        rowptr[lo + t] = excl;
        cur[t] = excl;
    }
    __syncthreads();
    for (int i = t; i < cnt; i += 1024) {
        int r = rec[i];
        int dlow = (r >> 20) & (BKT_SZ - 1);
        int pos = atomicAdd(&cur[dlow], 1);
        einfo[pos] = r & 0xFFFFF;
    }
}

// ---------------- aggregation ----------------
// SCALE_SRC: out[v] = relu(dinv[v]*(sum dinv[s]*h[s] + dinv[v]*h[v]) + b)
// else:      out[v] = relu(dinv[v]*(sum g[s] + g[v]) + b)   (g pre-scaled)
// 1 wave/node; half-wave per 256B bf16 row (uint2/lane); halves take even/odd
// edges; 8 gathers in flight per half (Little's law: 4-deep => 12KB/CU in
// flight = 2.7 TB/s measured; 8-deep targets ~22KB/CU => ~2x rate).
template <bool SCALE_SRC, bool OUT_BF16>
__global__ __launch_bounds__(256, 8) void agg_k(const unsigned short* __restrict__ Hb,
                                                const int* __restrict__ rowptr,
                                                const int* __restrict__ einfo,
                                                const float* __restrict__ dinv,
                                                const float* __restrict__ bias,
                                                void* __restrict__ out, int n) {
    int v = blockIdx.x * 4 + (threadIdx.x >> 6);
    int lane = threadIdx.x & 63;
    if (v >= n) return;
    int l = lane & 31, half = lane >> 5;
    const uint2* __restrict__ H = (const uint2*)Hb;  // row = 32 x uint2
    float dv = dinv[v];
    float a0 = 0.f, a1 = 0.f, a2 = 0.f, a3 = 0.f;
    if (half == 0) {
        uint2 hv = H[(size_t)v * 32 + l];  // self-loop term
        if (SCALE_SRC) {
            a0 = dv * bf_lo(hv.x); a1 = dv * bf_hi(hv.x);
            a2 = dv * bf_lo(hv.y); a3 = dv * bf_hi(hv.y);
        } else {
            a0 = bf_lo(hv.x); a1 = bf_hi(hv.x);
            a2 = bf_lo(hv.y); a3 = bf_hi(hv.y);
        }
    }
    int end = rowptr[v + 1];
    int i = rowptr[v] + half;
    // -------- 8-deep batch --------
    for (; i + 14 < end; i += 16) {
        int s0 = __builtin_nontemporal_load(&einfo[i]);
        int s1 = __builtin_nontemporal_load(&einfo[i + 2]);
        int s2 = __builtin_nontemporal_load(&einfo[i + 4]);
        int s3 = __builtin_nontemporal_load(&einfo[i + 6]);
        int s4 = __builtin_nontemporal_load(&einfo[i + 8]);
        int s5 = __builtin_nontemporal_load(&einfo[i + 10]);
        int s6 = __builtin_nontemporal_load(&einfo[i + 12]);
        int s7 = __builtin_nontemporal_load(&einfo[i + 14]);
        float d0 = 1.f, d1 = 1.f, d2 = 1.f, d3 = 1.f;
        float d4 = 1.f, d5 = 1.f, d6 = 1.f, d7 = 1.f;
        if (SCALE_SRC) {
            d0 = dinv[s0]; d1 = dinv[s1]; d2 = dinv[s2]; d3 = dinv[s3];
            d4 = dinv[s4]; d5 = dinv[s5]; d6 = dinv[s6]; d7 = dinv[s7];
        }
        uint2 v0 = H[(size_t)s0 * 32 + l];
        uint2 v1 = H[(size_t)s1 * 32 + l];
        uint2 v2 = H[(size_t)s2 * 32 + l];
        uint2 v3 = H[(size_t)s3 * 32 + l];
        uint2 v4 = H[(size_t)s4 * 32 + l];
        uint2 v5 = H[(size_t)s5 * 32 + l];
        uint2 v6 = H[(size_t)s6 * 32 + l];
        uint2 v7 = H[(size_t)s7 * 32 + l];
        if (SCALE_SRC) {
            a0 = fmaf(d0, bf_lo(v0.x), a0); a1 = fmaf(d0, bf_hi(v0.x), a1);
            a2 = fmaf(d0, bf_lo(v0.y), a2); a3 = fmaf(d0, bf_hi(v0.y), a3);
            a0 = fmaf(d1, bf_lo(v1.x), a0); a1 = fmaf(d1, bf_hi(v1.x), a1);
            a2 = fmaf(d1, bf_lo(v1.y), a2); a3 = fmaf(d1, bf_hi(v1.y), a3);
            a0 = fmaf(d2, bf_lo(v2.x), a0); a1 = fmaf(d2, bf_hi(v2.x), a1);
            a2 = fmaf(d2, bf_lo(v2.y), a2); a3 = fmaf(d2, bf_hi(v2.y), a3);
            a0 = fmaf(d3, bf_lo(v3.x), a0); a1 = fmaf(d3, bf_hi(v3.x), a1);
            a2 = fmaf(d3, bf_lo(v3.y), a2); a3 = fmaf(d3, bf_hi(v3.y), a3);
            a0 = fmaf(d4, bf_lo(v4.x), a0); a1 = fmaf(d4, bf_hi(v4.x), a1);
            a2 = fmaf(d4, bf_lo(v4.y), a2); a3 = fmaf(d4, bf_hi(v4.y), a3);
            a0 = fmaf(d5, bf_lo(v5.x), a0); a1 = fmaf(d5, bf_hi(v5.x), a1);
            a2 = fmaf(d5, bf_lo(v5.y), a2); a3 = fmaf(d5, bf_hi(v5.y), a3);
            a0 = fmaf(d6, bf_lo(v6.x), a0); a1 = fmaf(d6, bf_hi(v6.x), a1);
            a2 = fmaf(d6, bf_lo(v6.y), a2); a3 = fmaf(d6, bf_hi(v6.y), a3);
            a0 = fmaf(d7, bf_lo(v7.x), a0); a1 = fmaf(d7, bf_hi(v7.x), a1);
            a2 = fmaf(d7, bf_lo(v7.y), a2); a3 = fmaf(d7, bf_hi(v7.y), a3);
        } else {
            a0 += bf_lo(v0.x); a1 += bf_hi(v0.x); a2 += bf_lo(v0.y); a3 += bf_hi(v0.y);
            a0 += bf_lo(v1.x); a1 += bf_hi(v1.x); a2 += bf_lo(v1.y); a3 += bf_hi(v1.y);
            a0 += bf_lo(v2.x); a1 += bf_hi(v2.x); a2 += bf_lo(v2.y); a3 += bf_hi(v2.y);
            a0 += bf_lo(v3.x); a1 += bf_hi(v3.x); a2 += bf_lo(v3.y); a3 += bf_hi(v3.y);
            a0 += bf_lo(v4.x); a1 += bf_hi(v4.x); a2 += bf_lo(v4.y); a3 += bf_hi(v4.y);
            a0 += bf_lo(v5.x); a1 += bf_hi(v5.x); a2 += bf_lo(v5.y); a3 += bf_hi(v5.y);
            a0 += bf_lo(v6.x); a1 += bf_hi(v6.x); a2 += bf_lo(v6.y); a3 += bf_hi(v6.y);
            a0 += bf_lo(v7.x); a1 += bf_hi(v7.x); a2 += bf_lo(v7.y); a3 += bf_hi(v7.y);
        }
    }
    // -------- 4-deep batch --------
    for (; i + 6 < end; i += 8) {
        int s0 = __builtin_nontemporal_load(&einfo[i]);
        int s1 = __builtin_nontemporal_load(&einfo[i + 2]);
        int s2 = __builtin_nontemporal_load(&einfo[i + 4]);
        int s3 = __builtin_nontemporal_load(&einfo[i + 6]);
        float d0 = 1.f, d1 = 1.f, d2 = 1.f, d3 = 1.f;
        if (SCALE_SRC) { d0 = dinv[s0]; d1 = dinv[s1]; d2 = dinv[s2]; d3 = dinv[s3]; }
        uint2 v0 = H[(size_t)s0 * 32 + l];
        uint2 v1 = H[(size_t)s1 * 32 + l];
        uint2 v2 = H[(size_t)s2 * 32 + l];
        uint2 v3 = H[(size_t)s3 * 32 + l];
        if (SCALE_SRC) {
            a0 = fmaf(d0, bf_lo(v0.x), a0); a1 = fmaf(d0, bf_hi(v0.x), a1);
            a2 = fmaf(d0, bf_lo(v0.y), a2); a3 = fmaf(d0, bf_hi(v0.y), a3);
            a0 = fmaf(d1, bf_lo(v1.x), a0); a1 = fmaf(d1, bf_hi(v1.x), a1);
            a2 = fmaf(d1, bf_lo(v1.y), a2); a3 = fmaf(d1, bf_hi(v1.y), a3);
            a0 = fmaf(d2, bf_lo(v2.x), a0); a1 = fmaf(d2, bf_hi(v2.x), a1);
            a2 = fmaf(d2, bf_lo(v2.y), a2); a3 = fmaf(d2, bf_hi(v2.y), a3);
            a0 = fmaf(d3, bf_lo(v3.x), a0); a1 = fmaf(d3, bf_hi(v3.x), a1);
            a2 = fmaf(d3, bf_lo(v3.y), a2); a3 = fmaf(d3, bf_hi(v3.y), a3);
        } else {
            a0 += bf_lo(v0.x); a1 += bf_hi(v0.x); a2 += bf_lo(v0.y); a3 += bf_hi(v0.y);
            a0 += bf_lo(v1.x); a1 += bf_hi(v1.x); a2 += bf_lo(v1.y); a3 += bf_hi(v1.y);
            a0 += bf_lo(v2.x); a1 += bf_hi(v2.x); a2 += bf_lo(v2.y); a3 += bf_hi(v2.y);
            a0 += bf_lo(v3.x); a1 += bf_hi(v3.x); a2 += bf_lo(v3.y); a3 += bf_hi(v3.y);
        }
    }
    for (; i < end; i += 2) {
        int s = __builtin_nontemporal_load(&einfo[i]);
        float ds = SCALE_SRC ? dinv[s] : 1.f;
        uint2 vv = H[(size_t)s * 32 + l];
        if (SCALE_SRC) {
            a0 = fmaf(ds, bf_lo(vv.x), a0); a1 = fmaf(ds, bf_hi(vv.x), a1);
            a2 = fmaf(ds, bf_lo(vv.y), a2); a3 = fmaf(ds, bf_hi(vv.y), a3);
        } else {
            a0 += bf_lo(vv.x); a1 += bf_hi(vv.x); a2 += bf_lo(vv.y); a3 += bf_hi(vv.y);
        }
    }
    a0 += __shfl_xor(a0, 32);
    a1 += __shfl_xor(a1, 32);
    a2 += __shfl_xor(a2, 32);
    a3 += __shfl_xor(a3, 32);
    if (half == 0) {
        float4 bb = ((const float4*)bias)[l];
        float o0 = fmaxf(fmaf(dv, a0, bb.x), 0.f);
        float o1 = fmaxf(fmaf(dv, a1, bb.y), 0.f);
        float o2 = fmaxf(fmaf(dv, a2, bb.z), 0.f);
        float o3 = fmaxf(fmaf(dv, a3, bb.w), 0.f);
        if (OUT_BF16) {
            uint2e p;
            p.x = (unsigned int)f2bf(o0) | ((unsigned int)f2bf(o1) << 16);
            p.y = (unsigned int)f2bf(o2) | ((unsigned int)f2bf(o3) << 16);
            __builtin_nontemporal_store(p, (uint2e*)out + (size_t)v * 32 + l);
        } else {
            f32x4 o = {o0, o1, o2, o3};
            __builtin_nontemporal_store(o, (f32x4*)out + (size_t)v * 32 + l);
        }
    }
}

// ---------------- K4: layer-2 GEMM ------------------------------------------
__global__ __launch_bounds__(256) void gemm2_k(const unsigned short* __restrict__ A,
                                               const unsigned short* __restrict__ Wt,
                                               const float* __restrict__ dinv,
                                               unsigned short* __restrict__ Hb,
                                               int M, int K) {
    __shared__ unsigned short Bt[16384];
    gemm_body<true, true>(Bt, blockIdx.x, A, Wt, dinv, Hb, M, K);
}

static inline size_t align_up(size_t x, size_t a) { return (x + a - 1) & ~(a - 1); }

extern "C" void kernel_launch(void* const* d_in, const int* in_sizes, int n_in,
                              void* d_out, int out_size, void* d_ws, size_t ws_size,
                              hipStream_t stream) {
    const float* x  = (const float*)d_in[0];
    const int*   ei = (const int*)d_in[1];
    const float* W1 = (const float*)d_in[2];
    const float* b1 = (const float*)d_in[3];
    const float* W2 = (const float*)d_in[4];
    const float* b2 = (const float*)d_in[5];

    const int N = in_sizes[0] / DIN;   // 100000
    const int E = in_sizes[1] / 2;     // 1600000
    const int* src = ei;
    const int* dst = ei + E;
    const int NBKT = (N + BKT_SZ - 1) >> BKT_SHIFT;  // 196

    // workspace partition (round-1 layout)
    char* base_p = (char*)d_ws;
    size_t off = 0;
    int* bcnt = (int*)(base_p + off);       off = align_up(off + 256 * 4, 256);
    int* rowptr = (int*)(base_p + off);     off = align_up(off + (size_t)(N + 1) * 4, 256);
    float* dinv = (float*)(base_p + off);   off = align_up(off + (size_t)N * 4, 256);
    int* tmp = (int*)(base_p + off);        off = align_up(off + (size_t)NBKT * CAP * 4, 256);
    int* einfo = (int*)(base_p + off);      off = align_up(off + (size_t)E * 4, 256);
    unsigned short* Wt1 = (unsigned short*)(base_p + off); off = align_up(off + (size_t)128 * 256 * 2, 256);
    unsigned short* Wt2 = (unsigned short*)(base_p + off); off = align_up(off + (size_t)128 * 128 * 2, 256);
    unsigned short* hb  = (unsigned short*)(base_p + off); off = align_up(off + (size_t)N * 128 * 2, 256);
    unsigned short* a1b = (unsigned short*)(base_p + off); off = align_up(off + (size_t)N * 128 * 2, 256);

    float* out = (float*)d_out;

    const int NBB = 512;                                  // bucket blocks
    const int WTB = (256 * 128 + 128 * 128 + 255) / 256;  // 192 weight blocks
    const int GB = (N + 127) / 128;                       // 782 gemm blocks

    // K0: weight cvt + zero bcnt
    cvt_zero_k<<<WTB + 1, 256, 0, stream>>>(W1, W2, Wt1, Wt2, bcnt, WTB);
    // K1: bucket-binning || gemm1 (unscaled) in one kernel
    fused1_k<<<NBB + GB, 256, 0, stream>>>(src, dst, bcnt, tmp, E, N, NBB, x, Wt1, hb, N);
    // K2: per-bucket scan (inline 196-prefix) + dinv + rowptr + einfo scatter
    scatter2_k<<<NBKT, 1024, 0, stream>>>(tmp, bcnt, dinv, rowptr, einfo, N, NBKT);
    // K3: agg1 applies dinv[s] per source row (fma)
    agg_k<true, true><<<(N + 3) / 4, 256, 0, stream>>>(hb, rowptr, einfo, dinv, b1, a1b, N);
    // K4: layer-2 GEMM (dinv-scaled epilogue)
    gemm2_k<<<GB, 256, 0, stream>>>(a1b, Wt2, dinv, hb, N, DH);
    // K5: agg2 -> fp32 out
    agg_k<false, false><<<(N + 3) / 4, 256, 0, stream>>>(hb, rowptr, einfo, dinv, b2, out, N);
}